// Round 6
// baseline (689.674 us; speedup 1.0000x reference)
//
#include <hip/hip_runtime.h>
#include <math.h>

#define B_ 2
#define N_ 25000
#define E_ 400000
#define D_ 128
#define NRBF 64

#define TPB 256               // 4 waves
#define TILE 64               // edges per tile-step (16/wave)
#define NTILES 10             // grid 1250 blocks feeds 3-block/CU capacity (768 slots)
#define EPB (TILE * NTILES)   // 640 edges per block
#define WCH (EPB / 4)         // 160 edges per wave
#define GCH (EPB / 16)        // 40 edges per (wave, lane-quad) chunk
#define NBLK (E_ / EPB)       // 625 blocks per batch

typedef short bf8   __attribute__((ext_vector_type(8)));   // MFMA A/B frag (8 bf16)
typedef float f32x4 __attribute__((ext_vector_type(4)));   // MFMA C/D frag
typedef float vf8   __attribute__((ext_vector_type(8)));
typedef float vf16  __attribute__((ext_vector_type(16)));

// f32 -> bf16 bits, round-nearest-even
__device__ __forceinline__ short f2bf(float f) {
    union { float f; unsigned u; } v; v.f = f;
    unsigned r = (v.u + 0x7FFFu + ((v.u >> 16) & 1u)) >> 16;
    return (short)r;
}
// shifted softplus: softplus(x) - ln(2)
__device__ __forceinline__ float ssp(float x) {
    return fmaxf(x, 0.0f) + __logf(1.0f + __expf(-fabsf(x))) - 0.69314718056f;
}

// launch_bounds(,3): 170-reg budget; loop keeps ~160 live after dropping
// the w1r hoist (-64) and b1s (-32). 3 blocks/CU by BOTH regs and LDS.
__global__ __launch_bounds__(TPB, 3)
void cfconv_kernel(const float* __restrict__ af,      // [B,N,D]
                   const float* __restrict__ dist,    // [B,E]
                   const int*   __restrict__ idx_j,   // [E]
                   const int*   __restrict__ seg_i,   // [E] (sorted)
                   const float* __restrict__ centers, // [NRBF]
                   const float* __restrict__ gam,     // [NRBF]
                   const float* __restrict__ W1,      // [NRBF,D]
                   const float* __restrict__ b1,      // [D]
                   const float* __restrict__ W2,      // [D,D]
                   const float* __restrict__ b2,      // [D]
                   float* __restrict__ out)           // [B,N,D]
{
    const int t    = threadIdx.x;        // 0..255
    const int lane = t & 63;
    const int w    = t >> 6;             // wave id 0..3
    const int g    = lane >> 4;          // lane quad 0..3
    const int c0   = lane & 15;
    const int b    = blockIdx.y;
    const int e0   = blockIdx.x * EPB;

    // fragment-ready bf16 weights: [c][g][n][j] ; B-frag k = c*32+g*8+j
    __shared__ __align__(16) short W1f[2 * 4 * D_ * 8];     // 16 KB, loop-resident
    __shared__ __align__(16) short W2f[4 * 4 * D_ * 8];     // 32 KB, loop-resident
    __shared__ float b1f[D_];                               // 512 B
    // total ~48.5 KB -> 3 blocks/CU (145.5 <= 160 KB)

    // ---- prep: weights -> bf16 fragment layout (once per block)
    for (int i = t; i < NRBF * D_; i += TPB) {
        const int k = i >> 7, n = i & 127;
        W1f[(((k >> 5) * 4 + ((k >> 3) & 3)) * D_ + n) * 8 + (k & 7)] = f2bf(W1[i]);
    }
    for (int i = t; i < D_ * D_; i += TPB) {
        const int k = i >> 7, n = i & 127;
        W2f[(((k >> 5) * 4 + ((k >> 3) & 3)) * D_ + n) * 8 + (k & 7)] = f2bf(W2[i]);
    }
    if (t < D_) b1f[t] = b1[t];
    __syncthreads();   // the ONLY block barrier: weights ready

    // ---- per-lane constants (loop-invariant registers kept deliberately small)
    vf8 b2r;
    #pragma unroll
    for (int nt = 0; nt < 8; ++nt) b2r[nt] = b2[nt * 16 + c0];

    // RBF params for exactly the k-slices this lane's rbf fragments need:
    // a0 covers k = g*8+j (j=0..7), a1 covers k = 32+g*8+j
    vf16 gkr, ckr;
    #pragma unroll
    for (int j = 0; j < 8; ++j) {
        gkr[j]     = gam[g * 8 + j];
        gkr[8 + j] = gam[32 + g * 8 + j];
        ckr[j]     = centers[g * 8 + j];
        ckr[8 + j] = centers[32 + g * 8 + j];
    }

    // ds_permute target-lane byte addresses (fixed permutations, loop-invariant):
    // inst1: g -> 2*(g&1) + (g>>1) ; inst2: g -> 2*(1-(g&1)) + (g>>1)
    const int addr1 = ((((g & 1) << 1) | (g >> 1)) * 16 + c0) * 4;
    const int addr2 = (((((g & 1) ^ 1) << 1) | (g >> 1)) * 16 + c0) * 4;

    const float* dist_b = dist + (size_t)b * E_;
    const float* af_b   = af   + (size_t)b * N_ * D_;
    float*       out_b  = out  + (size_t)b * N_ * D_;

    const int ebase = e0 + w * WCH + g * GCH;   // epilogue: this lane-quad's chunk
    // rbf phase: lane (g,c0) supplies edge row m=c0 of its wave's 16-edge tile
    const int eArow = e0 + w * WCH + (c0 >> 2) * GCH + (c0 & 3);

    int cur_seg = -1;
    vf8 pend = (vf8)0.0f;

    // ---- prologue: scalar state for tile 0 (one tile ahead of use)
    float dd = dist_b[eArow];
    int idx[4], sgp[4];
    #pragma unroll
    for (int r = 0; r < 4; ++r) {
        idx[r] = idx_j[ebase + r];
        sgp[r] = seg_i[ebase + r];
    }

    for (int s = 0; s < NTILES; ++s) {
        // ===== gather loads for THIS tile (addresses prefetched last iter;
        // consumed in epilogue -> latency hidden under A+B+C compute) =====
        float rows[4][8];
        #pragma unroll
        for (int r = 0; r < 4; ++r) {
            const float* rowp = af_b + (size_t)idx[r] * D_ + c0;
            #pragma unroll
            for (int nt = 0; nt < 8; ++nt) rows[r][nt] = rowp[nt * 16];
        }

        // ===== Phase A: RBF -> fragments fully in-register =====
        // lane (g,c0) holds (edge index c0, k = c*32+g*8+j) — valid as A OR B frag
        bf8 a0, a1;
        #pragma unroll
        for (int j = 0; j < 8; ++j) {
            const float x0 = dd - ckr[j];
            const float x1 = dd - ckr[8 + j];
            a0[j] = f2bf(__expf(-gkr[j] * x0 * x0));
            a1[j] = f2bf(__expf(-gkr[8 + j] * x1 * x1));
        }

        // ===== prefetch next tile's scalars (consumed next iteration) =====
        float ddN = 0.0f;
        int idxN[4] = {0, 0, 0, 0}, sgN[4] = {0, 0, 0, 0};
        if (s + 1 < NTILES) {
            ddN = dist_b[eArow + (s + 1) * 4];
            #pragma unroll
            for (int r = 0; r < 4; ++r) {
                idxN[r] = idx_j[ebase + (s + 1) * 4 + r];
                sgN[r]  = seg_i[ebase + (s + 1) * 4 + r];
            }
        }

        // ===== Phase B: swapped GEMM1 (h1^T = W1^T @ rbf^T), ssp, and
        // in-register transpose to GEMM2 A-frags via ds_permute =====
        // W1 frags re-read from resident W1f each tile (regs traded for occupancy).
        // D1: lane (g,c0) reg r = h1[edge=c0][k2=nt*16+g*4+r].
        // GEMM2 A-frag needs h1[edge=c0][k=c*32+g*8+j]: same c0 column,
        // cross-g exchange. Per (c,pair): 2 staged ds_permute + 2 selects.
        unsigned pw[4][4];
        #pragma unroll
        for (int c = 0; c < 4; ++c) {
            unsigned Pl[2][2];   // packed bf16 pairs for nt=2c (Pl[0]) and 2c+1 (Pl[1])
            #pragma unroll
            for (int h = 0; h < 2; ++h) {
                const int nt = 2 * c + h;
                const bf8 wa = *(const bf8*)&W1f[((0 * 4 + g) * D_ + nt * 16 + c0) * 8];
                const bf8 wb = *(const bf8*)&W1f[((1 * 4 + g) * D_ + nt * 16 + c0) * 8];
                f32x4 acc = {0.f, 0.f, 0.f, 0.f};
                acc = __builtin_amdgcn_mfma_f32_16x16x32_bf16(wa, a0, acc, 0, 0, 0);
                acc = __builtin_amdgcn_mfma_f32_16x16x32_bf16(wb, a1, acc, 0, 0, 0);
                #pragma unroll
                for (int pr = 0; pr < 2; ++pr) {
                    const float h0 = ssp(acc[2 * pr]     + b1f[nt * 16 + g * 4 + 2 * pr]);
                    const float h1v = ssp(acc[2 * pr + 1] + b1f[nt * 16 + g * 4 + 2 * pr + 1]);
                    Pl[h][pr] = (unsigned)(unsigned short)f2bf(h0)
                              | ((unsigned)(unsigned short)f2bf(h1v) << 16);
                }
            }
            #pragma unroll
            for (int pr = 0; pr < 2; ++pr) {
                // inst1: even-g lanes carry nt=2c, odd-g carry nt=2c+1
                const int s1 = (g & 1) ? (int)Pl[1][pr] : (int)Pl[0][pr];
                // inst2: roles swapped
                const int s2 = (g & 1) ? (int)Pl[0][pr] : (int)Pl[1][pr];
                const int r1 = __builtin_amdgcn_ds_permute(addr1, s1);
                const int r2 = __builtin_amdgcn_ds_permute(addr2, s2);
                // consumers g<2 got their j<4 word from inst1, j>=4 from inst2;
                // consumers g>=2 the opposite.
                pw[c][pr]     = (g < 2) ? (unsigned)r1 : (unsigned)r2;  // j01/j23
                pw[c][2 + pr] = (g < 2) ? (unsigned)r2 : (unsigned)r1;  // j45/j67
            }
        }
        bf8 pc[4];
        #pragma unroll
        for (int c = 0; c < 4; ++c) {
            union { unsigned u[4]; bf8 v; } tu;
            tu.u[0] = pw[c][0]; tu.u[1] = pw[c][1];
            tu.u[2] = pw[c][2]; tu.u[3] = pw[c][3];
            pc[c] = tu.v;
        }

        // ===== Phase C: GEMM2 (filters = h1 @ W2), ssp, gather*filter, scatter =====
        {
            f32x4 facc[8];
            #pragma unroll
            for (int nt = 0; nt < 8; ++nt) {
                const bf8 w0 = *(const bf8*)&W2f[((0 * 4 + g) * D_ + nt * 16 + c0) * 8];
                const bf8 w1v = *(const bf8*)&W2f[((1 * 4 + g) * D_ + nt * 16 + c0) * 8];
                const bf8 w2v = *(const bf8*)&W2f[((2 * 4 + g) * D_ + nt * 16 + c0) * 8];
                const bf8 w3v = *(const bf8*)&W2f[((3 * 4 + g) * D_ + nt * 16 + c0) * 8];
                f32x4 acc = {0.f, 0.f, 0.f, 0.f};
                acc = __builtin_amdgcn_mfma_f32_16x16x32_bf16(pc[0], w0,  acc, 0, 0, 0);
                acc = __builtin_amdgcn_mfma_f32_16x16x32_bf16(pc[1], w1v, acc, 0, 0, 0);
                acc = __builtin_amdgcn_mfma_f32_16x16x32_bf16(pc[2], w2v, acc, 0, 0, 0);
                acc = __builtin_amdgcn_mfma_f32_16x16x32_bf16(pc[3], w3v, acc, 0, 0, 0);
                facc[nt] = acc;
            }
            // epilogue: quad g owns edges ebase + s*4 + r; lane handles cols c0+16*nt
            #pragma unroll
            for (int r = 0; r < 4; ++r) {
                const int sg = sgp[r];
                vf8 msg;
                #pragma unroll
                for (int nt = 0; nt < 8; ++nt) {
                    const float fv = ssp(facc[nt][r] + b2r[nt]);
                    msg[nt] = rows[r][nt] * fv;
                }
                if (sg != cur_seg) {
                    if (cur_seg >= 0) {
                        float* o = out_b + (size_t)cur_seg * D_ + c0;
                        #pragma unroll
                        for (int nt = 0; nt < 8; ++nt) atomicAdd(o + nt * 16, pend[nt]);
                    }
                    cur_seg = sg;
                    pend = msg;
                } else {
                    pend += msg;
                }
            }
        }

        // commit prefetched scalars for next tile
        dd = ddN;
        #pragma unroll
        for (int r = 0; r < 4; ++r) { idx[r] = idxN[r]; sgp[r] = sgN[r]; }
    }
    if (cur_seg >= 0) {
        float* o = out_b + (size_t)cur_seg * D_ + c0;
        #pragma unroll
        for (int nt = 0; nt < 8; ++nt) atomicAdd(o + nt * 16, pend[nt]);
    }
}

extern "C" void kernel_launch(void* const* d_in, const int* in_sizes, int n_in,
                              void* d_out, int out_size, void* d_ws, size_t ws_size,
                              hipStream_t stream) {
    const float* af      = (const float*)d_in[0];
    const float* dist    = (const float*)d_in[1];
    const int*   idx_j   = (const int*)d_in[2];
    const int*   seg_i   = (const int*)d_in[3];
    const float* centers = (const float*)d_in[4];
    const float* gam     = (const float*)d_in[5];
    const float* W1      = (const float*)d_in[6];
    const float* b1      = (const float*)d_in[7];
    const float* W2      = (const float*)d_in[8];
    const float* b2      = (const float*)d_in[9];
    float* out = (float*)d_out;

    hipMemsetAsync(out, 0, (size_t)out_size * sizeof(float), stream);

    dim3 grid(NBLK, B_);
    cfconv_kernel<<<grid, TPB, 0, stream>>>(af, dist, idx_j, seg_i,
                                            centers, gam, W1, b1, W2, b2, out);
}

// Round 8
// 258.890 us; speedup vs baseline: 2.6640x; 2.6640x over previous
//
#include <hip/hip_runtime.h>
#include <math.h>

#define B_ 2
#define N_ 25000
#define E_ 400000
#define D_ 128
#define NRBF 64

#define TPB 256               // 4 waves
#define TILE 64               // edges per tile-step (16/wave)
#define NTILES 25
#define EPB (TILE * NTILES)   // 1600 edges per block
#define WCH (EPB / 4)         // 400 edges per wave
#define GCH (EPB / 16)        // 100 edges per (wave, lane-quad) chunk
#define NBLK (E_ / EPB)       // 250 blocks per batch

typedef short bf8   __attribute__((ext_vector_type(8)));   // MFMA A/B frag (8 bf16)
typedef float f32x4 __attribute__((ext_vector_type(4)));   // MFMA C/D frag
typedef float vf8   __attribute__((ext_vector_type(8)));
typedef float vf16  __attribute__((ext_vector_type(16)));

// f32 -> bf16 bits, round-nearest-even
__device__ __forceinline__ short f2bf(float f) {
    union { float f; unsigned u; } v; v.f = f;
    unsigned r = (v.u + 0x7FFFu + ((v.u >> 16) & 1u)) >> 16;
    return (short)r;
}
// shifted softplus: softplus(x) - ln(2)
__device__ __forceinline__ float ssp(float x) {
    return fmaxf(x, 0.0f) + __logf(1.0f + __expf(-fabsf(x))) - 0.69314718056f;
}

__global__ __launch_bounds__(TPB, 2)
void cfconv_kernel(const float* __restrict__ af,      // [B,N,D]
                   const float* __restrict__ dist,    // [B,E]
                   const int*   __restrict__ idx_j,   // [E]
                   const int*   __restrict__ seg_i,   // [E] (sorted)
                   const float* __restrict__ centers, // [NRBF]
                   const float* __restrict__ gam,     // [NRBF]
                   const float* __restrict__ W1,      // [NRBF,D]
                   const float* __restrict__ b1,      // [D]
                   const float* __restrict__ W2,      // [D,D]
                   const float* __restrict__ b2,      // [D]
                   float* __restrict__ out)           // [B,N,D]
{
    const int t    = threadIdx.x;        // 0..255
    const int lane = t & 63;
    const int w    = t >> 6;             // wave id 0..3
    const int g    = lane >> 4;          // lane quad 0..3
    const int c0   = lane & 15;
    const int b    = blockIdx.y;
    const int e0   = blockIdx.x * EPB;

    // fragment-ready bf16 weights: [c][g][n][j] ; B[k][n], k = c*32+g*8+j
    __shared__ __align__(16) short W1f[2 * 4 * D_ * 8];     // 16 KB
    __shared__ __align__(16) short W2f[4 * 4 * D_ * 8];     // 32 KB
    __shared__ __align__(16) short A1 [4 * 2 * 4 * 16 * 8]; //  8 KB [w][c][g][m][j]
    __shared__ __align__(16) short A2 [4 * 4 * 4 * 16 * 8]; // 16 KB [w][c][g][m][j]
    __shared__ float gs[NRBF], cs[NRBF];

    // ---- prep: weights -> bf16 fragment layout (once per block)
    for (int i = t; i < NRBF * D_; i += TPB) {
        const int k = i >> 7, n = i & 127;
        W1f[(((k >> 5) * 4 + ((k >> 3) & 3)) * D_ + n) * 8 + (k & 7)] = f2bf(W1[i]);
    }
    for (int i = t; i < D_ * D_; i += TPB) {
        const int k = i >> 7, n = i & 127;
        W2f[(((k >> 5) * 4 + ((k >> 3) & 3)) * D_ + n) * 8 + (k & 7)] = f2bf(W2[i]);
    }
    if (t < NRBF) { gs[t] = gam[t]; cs[t] = centers[t]; }
    __syncthreads();

    // ---- per-lane constants
    vf8 b1r, b2r;
    #pragma unroll
    for (int nt = 0; nt < 8; ++nt) {
        b1r[nt] = b1[nt * 16 + c0];
        b2r[nt] = b2[nt * 16 + c0];
    }
    // rbf params for this thread's 16-k slice (phase A role: el = t>>2, kq = t&3)
    const int el = t >> 2, kq = t & 3;
    const int we = el >> 4, me = el & 15;
    vf16 gkr, ckr;
    #pragma unroll
    for (int kk = 0; kk < 16; ++kk) { gkr[kk] = gs[kq * 16 + kk]; ckr[kk] = cs[kq * 16 + kk]; }

    const float* dist_b = dist + (size_t)b * E_;
    const float* af_b   = af   + (size_t)b * N_ * D_;
    float*       out_b  = out  + (size_t)b * N_ * D_;

    const int ebase = e0 + w * WCH + g * GCH;   // this lane-quad's contiguous chunk
    const int eArow = e0 + we * WCH + (me >> 2) * GCH + (me & 3);  // phase A role

    int cur_seg = -1;
    vf8 pend = (vf8)0.0f;

    // ---- prologue: scalar state for tile 0 (prefetched one tile ahead after)
    float dd = dist_b[eArow];
    int idx[4], sgp[4];
    #pragma unroll
    for (int r = 0; r < 4; ++r) {
        idx[r] = idx_j[ebase + r];
        sgp[r] = seg_i[ebase + r];
    }

    for (int s = 0; s < NTILES; ++s) {
        // ===== Phase A: RBF for 64 edges x 64 k, bf16, A-frag layout =====
        {
            short rb[16];
            #pragma unroll
            for (int kk = 0; kk < 16; ++kk) {
                const float x = dd - ckr[kk];
                rb[kk] = f2bf(__expf(-gkr[kk] * x * x));
            }
            // k = kq*16+kk -> c = kq>>1, g2 = (kq&1)*2 + (kk>>3), j = kk&7
            bf8 lo, hi;
            #pragma unroll
            for (int j = 0; j < 8; ++j) { lo[j] = rb[j]; hi[j] = rb[8 + j]; }
            const int base = (((we * 2 + (kq >> 1)) * 4 + (kq & 1) * 2) * 16 + me) * 8;
            *(bf8*)&A1[base]            = lo;   // g2 even
            *(bf8*)&A1[base + 16 * 8]   = hi;   // g2 odd (+1 row of 16m*8j)
        }

        // ===== prefetch next tile's scalars (drained at barrier (1); consumed
        // next iteration, so the drain costs nothing) =====
        float ddN = 0.0f;
        int idxN[4] = {0, 0, 0, 0}, sgN[4] = {0, 0, 0, 0};
        if (s + 1 < NTILES) {
            ddN = dist_b[eArow + (s + 1) * 4];
            #pragma unroll
            for (int r = 0; r < 4; ++r) {
                idxN[r] = idx_j[ebase + (s + 1) * 4 + r];
                sgN[r]  = seg_i[ebase + (s + 1) * 4 + r];
            }
        }
        __syncthreads();   // (1) A1 ready; also guards A2(s-1) reads vs writes below

        // ===== Phase B: GEMM1 (h1 = rbf @ W1), ssp, transpose-store to A2 =====
        {
            const bf8 a0 = *(const bf8*)&A1[(((w * 2 + 0) * 4 + g) * 16 + c0) * 8];
            const bf8 a1 = *(const bf8*)&A1[(((w * 2 + 1) * 4 + g) * 16 + c0) * 8];
            f32x4 hh[8];
            #pragma unroll
            for (int nt = 0; nt < 8; ++nt) {
                const bf8 w0 = *(const bf8*)&W1f[((0 * 4 + g) * D_ + nt * 16 + c0) * 8];
                const bf8 w1 = *(const bf8*)&W1f[((1 * 4 + g) * D_ + nt * 16 + c0) * 8];
                f32x4 acc = {0.f, 0.f, 0.f, 0.f};
                acc = __builtin_amdgcn_mfma_f32_16x16x32_bf16(a0, w0, acc, 0, 0, 0);
                acc = __builtin_amdgcn_mfma_f32_16x16x32_bf16(a1, w1, acc, 0, 0, 0);
                hh[nt] = acc;
            }
            // value (row m' = g*4+r, col k2 = nt*16+c0) -> A2[w][nt>>1][(nt&1)*2+(c0>>3)][m'][c0&7]
            #pragma unroll
            for (int nt = 0; nt < 8; ++nt) {
                const int shb = (((w * 4 + (nt >> 1)) * 4 + ((nt & 1) * 2 + (c0 >> 3))) * 16) * 8 + (c0 & 7);
                #pragma unroll
                for (int r = 0; r < 4; ++r) {
                    const float hv = ssp(hh[nt][r] + b1r[nt]);
                    A2[shb + (g * 4 + r) * 8] = f2bf(hv);
                }
            }
        }
        __syncthreads();   // (2) A2 ready

        // ===== Phase C: GEMM2 (filters = h1 @ W2), ssp, gather*filter, scatter =====
        {
            // gather loads issued FIRST in the drain-free window: idx was
            // prefetched last tile, so addresses are ready; GEMM2's 32 MFMAs
            // + 32 LDS b128 reads (~400-600 cyc) cover the gather latency.
            float rows[4][8];
            #pragma unroll
            for (int r = 0; r < 4; ++r) {
                const float* rowp = af_b + (size_t)idx[r] * D_ + c0;
                #pragma unroll
                for (int nt = 0; nt < 8; ++nt) rows[r][nt] = rowp[nt * 16];
            }

            const bf8 p0 = *(const bf8*)&A2[(((w * 4 + 0) * 4 + g) * 16 + c0) * 8];
            const bf8 p1 = *(const bf8*)&A2[(((w * 4 + 1) * 4 + g) * 16 + c0) * 8];
            const bf8 p2 = *(const bf8*)&A2[(((w * 4 + 2) * 4 + g) * 16 + c0) * 8];
            const bf8 p3 = *(const bf8*)&A2[(((w * 4 + 3) * 4 + g) * 16 + c0) * 8];
            f32x4 facc[8];
            #pragma unroll
            for (int nt = 0; nt < 8; ++nt) {
                const bf8 w0 = *(const bf8*)&W2f[((0 * 4 + g) * D_ + nt * 16 + c0) * 8];
                const bf8 w1 = *(const bf8*)&W2f[((1 * 4 + g) * D_ + nt * 16 + c0) * 8];
                const bf8 w2 = *(const bf8*)&W2f[((2 * 4 + g) * D_ + nt * 16 + c0) * 8];
                const bf8 w3 = *(const bf8*)&W2f[((3 * 4 + g) * D_ + nt * 16 + c0) * 8];
                f32x4 acc = {0.f, 0.f, 0.f, 0.f};
                acc = __builtin_amdgcn_mfma_f32_16x16x32_bf16(p0, w0, acc, 0, 0, 0);
                acc = __builtin_amdgcn_mfma_f32_16x16x32_bf16(p1, w1, acc, 0, 0, 0);
                acc = __builtin_amdgcn_mfma_f32_16x16x32_bf16(p2, w2, acc, 0, 0, 0);
                acc = __builtin_amdgcn_mfma_f32_16x16x32_bf16(p3, w3, acc, 0, 0, 0);
                facc[nt] = acc;
            }
            // epilogue: lane-quad g owns edges ebase + s*4 + r, lane handles cols c0+16*nt
            #pragma unroll
            for (int r = 0; r < 4; ++r) {
                const int sg = sgp[r];
                vf8 msg;
                #pragma unroll
                for (int nt = 0; nt < 8; ++nt) {
                    const float fv = ssp(facc[nt][r] + b2r[nt]);
                    msg[nt] = rows[r][nt] * fv;
                }
                if (sg != cur_seg) {
                    if (cur_seg >= 0) {
                        float* o = out_b + (size_t)cur_seg * D_ + c0;
                        #pragma unroll
                        for (int nt = 0; nt < 8; ++nt) atomicAdd(o + nt * 16, pend[nt]);
                    }
                    cur_seg = sg;
                    pend = msg;
                } else {
                    pend += msg;
                }
            }
        }

        // commit prefetched scalars for next tile
        dd = ddN;
        #pragma unroll
        for (int r = 0; r < 4; ++r) { idx[r] = idxN[r]; sgp[r] = sgN[r]; }
        // next Phase A writes A1 only after barrier (1); A2 race guarded by (1) too
    }
    if (cur_seg >= 0) {
        float* o = out_b + (size_t)cur_seg * D_ + c0;
        #pragma unroll
        for (int nt = 0; nt < 8; ++nt) atomicAdd(o + nt * 16, pend[nt]);
    }
}

extern "C" void kernel_launch(void* const* d_in, const int* in_sizes, int n_in,
                              void* d_out, int out_size, void* d_ws, size_t ws_size,
                              hipStream_t stream) {
    const float* af      = (const float*)d_in[0];
    const float* dist    = (const float*)d_in[1];
    const int*   idx_j   = (const int*)d_in[2];
    const int*   seg_i   = (const int*)d_in[3];
    const float* centers = (const float*)d_in[4];
    const float* gam     = (const float*)d_in[5];
    const float* W1      = (const float*)d_in[6];
    const float* b1      = (const float*)d_in[7];
    const float* W2      = (const float*)d_in[8];
    const float* b2      = (const float*)d_in[9];
    float* out = (float*)d_out;

    hipMemsetAsync(out, 0, (size_t)out_size * sizeof(float), stream);

    dim3 grid(NBLK, B_);
    cfconv_kernel<<<grid, TPB, 0, stream>>>(af, dist, idx_j, seg_i,
                                            centers, gam, W1, b1, W2, b2, out);
}

// Round 12
// 256.691 us; speedup vs baseline: 2.6868x; 1.0086x over previous
//
#include <hip/hip_runtime.h>
#include <math.h>

#define B_ 2
#define N_ 25000
#define E_ 400000
#define D_ 128
#define NRBF 64

#define TPB 256               // 4 waves
#define TILE 64               // edges per tile-step (16/wave)
#define NTILES 25
#define EPB (TILE * NTILES)   // 1600 edges per block
#define WCH (EPB / 4)         // 400 edges per wave
#define GCH (EPB / 16)        // 100 edges per (wave, lane-quad) chunk
#define NBLK (E_ / EPB)       // 250 blocks per batch

typedef short bf8   __attribute__((ext_vector_type(8)));   // MFMA A/B frag (8 bf16)
typedef float f32x4 __attribute__((ext_vector_type(4)));   // MFMA C/D frag
typedef float vf8   __attribute__((ext_vector_type(8)));
typedef float vf16  __attribute__((ext_vector_type(16)));

// f32 -> bf16 bits, round-nearest-even (prologue only; loop uses cvt_pk)
__device__ __forceinline__ short f2bf(float f) {
    union { float f; unsigned u; } v; v.f = f;
    unsigned r = (v.u + 0x7FFFu + ((v.u >> 16) & 1u)) >> 16;
    return (short)r;
}
// HW packed f32x2 -> bf16x2 (RNE), gfx950. No builtin — inline asm (T12/m240).
__device__ __forceinline__ unsigned cvt_pk_bf16(float lo, float hi) {
    unsigned r;
    asm("v_cvt_pk_bf16_f32 %0, %1, %2" : "=v"(r) : "v"(lo), "v"(hi));
    return r;
}
// shifted softplus: softplus(x) - ln(2)
__device__ __forceinline__ float ssp(float x) {
    return fmaxf(x, 0.0f) + __logf(1.0f + __expf(-fabsf(x))) - 0.69314718056f;
}

__global__ __launch_bounds__(TPB, 2)
void cfconv_kernel(const float* __restrict__ af,      // [B,N,D]
                   const float* __restrict__ dist,    // [B,E]
                   const int*   __restrict__ idx_j,   // [E]
                   const int*   __restrict__ seg_i,   // [E] (sorted)
                   const float* __restrict__ centers, // [NRBF]
                   const float* __restrict__ gam,     // [NRBF]
                   const float* __restrict__ W1,      // [NRBF,D]
                   const float* __restrict__ b1,      // [D]
                   const float* __restrict__ W2,      // [D,D]
                   const float* __restrict__ b2,      // [D]
                   float* __restrict__ out)           // [B,N,D]
{
    const int t    = threadIdx.x;        // 0..255
    const int lane = t & 63;
    const int w    = t >> 6;             // wave id 0..3
    const int g    = lane >> 4;          // lane quad 0..3
    const int c0   = lane & 15;
    const int b    = blockIdx.y;
    const int e0   = blockIdx.x * EPB;

    // fragment-ready bf16 weights: [c][g][n][j] ; B[k][n], k = c*32+g*8+j
    __shared__ __align__(16) short W1f[2 * 4 * D_ * 8];     // 16 KB
    __shared__ __align__(16) short W2f[4 * 4 * D_ * 8];     // 32 KB
    __shared__ __align__(16) short A1 [4 * 2 * 4 * 16 * 8]; //  8 KB [w][c][g][m][j]
    __shared__ __align__(16) short A2 [4 * 4 * 4 * 16 * 8]; // 16 KB [w][c][g][m][j]
    __shared__ float gs[NRBF], cs[NRBF];

    // ---- prep: weights -> bf16 fragment layout (once per block)
    for (int i = t; i < NRBF * D_; i += TPB) {
        const int k = i >> 7, n = i & 127;
        W1f[(((k >> 5) * 4 + ((k >> 3) & 3)) * D_ + n) * 8 + (k & 7)] = f2bf(W1[i]);
    }
    for (int i = t; i < D_ * D_; i += TPB) {
        const int k = i >> 7, n = i & 127;
        W2f[(((k >> 5) * 4 + ((k >> 3) & 3)) * D_ + n) * 8 + (k & 7)] = f2bf(W2[i]);
    }
    if (t < NRBF) { gs[t] = gam[t]; cs[t] = centers[t]; }
    __syncthreads();

    // ---- per-lane constants
    vf8 b1r, b2r;
    #pragma unroll
    for (int nt = 0; nt < 8; ++nt) {
        b1r[nt] = b1[nt * 16 + c0];
        b2r[nt] = b2[nt * 16 + c0];
    }
    // rbf params for this thread's 16-k slice (phase A role: el = t>>2, kq = t&3)
    const int el = t >> 2, kq = t & 3;
    const int we = el >> 4, me = el & 15;
    vf16 gkr, ckr;
    #pragma unroll
    for (int kk = 0; kk < 16; ++kk) { gkr[kk] = gs[kq * 16 + kk]; ckr[kk] = cs[kq * 16 + kk]; }

    const float* dist_b = dist + (size_t)b * E_;
    const float* af_b   = af   + (size_t)b * N_ * D_;
    float*       out_b  = out  + (size_t)b * N_ * D_;

    const int ebase = e0 + w * WCH + g * GCH;   // this lane-quad's contiguous chunk
    const int eArow = e0 + we * WCH + (me >> 2) * GCH + (me & 3);  // phase A role

    int cur_seg = -1;
    vf8 pend = (vf8)0.0f;

    // ---- prologue: scalar state for tile 0 (prefetched one tile ahead after)
    float dd = dist_b[eArow];
    int idx[4], sgp[4];
    #pragma unroll
    for (int r = 0; r < 4; ++r) {
        idx[r] = idx_j[ebase + r];
        sgp[r] = seg_i[ebase + r];
    }

    for (int s = 0; s < NTILES; ++s) {
        // ===== Phase A: RBF for 64 edges x 64 k, bf16, A-frag layout =====
        {
            float er[16];
            #pragma unroll
            for (int kk = 0; kk < 16; ++kk) {
                const float x = dd - ckr[kk];
                er[kk] = __expf(-gkr[kk] * x * x);
            }
            // pack pairs with HW cvt (word q of a bf8 = {elem 2q, elem 2q+1})
            union { unsigned u[4]; bf8 v; } lo, hi;
            #pragma unroll
            for (int q = 0; q < 4; ++q) {
                lo.u[q] = cvt_pk_bf16(er[2 * q],     er[2 * q + 1]);
                hi.u[q] = cvt_pk_bf16(er[8 + 2 * q], er[9 + 2 * q]);
            }
            // k = kq*16+kk -> c = kq>>1, g2 = (kq&1)*2 + (kk>>3), j = kk&7
            const int base = (((we * 2 + (kq >> 1)) * 4 + (kq & 1) * 2) * 16 + me) * 8;
            *(bf8*)&A1[base]            = lo.v;   // g2 even
            *(bf8*)&A1[base + 16 * 8]   = hi.v;   // g2 odd (+1 row of 16m*8j)
        }

        // ===== prefetch next tile's scalars (drained at barrier (1); consumed
        // next iteration, so the drain costs nothing) =====
        float ddN = 0.0f;
        int idxN[4] = {0, 0, 0, 0}, sgN[4] = {0, 0, 0, 0};
        if (s + 1 < NTILES) {
            ddN = dist_b[eArow + (s + 1) * 4];
            #pragma unroll
            for (int r = 0; r < 4; ++r) {
                idxN[r] = idx_j[ebase + (s + 1) * 4 + r];
                sgN[r]  = seg_i[ebase + (s + 1) * 4 + r];
            }
        }
        __syncthreads();   // (1) A1 ready; also guards A2(s-1) reads vs writes below

        // ===== Phase B: GEMM1 (h1 = rbf @ W1), ssp, transpose-store to A2 =====
        {
            const bf8 a0 = *(const bf8*)&A1[(((w * 2 + 0) * 4 + g) * 16 + c0) * 8];
            const bf8 a1 = *(const bf8*)&A1[(((w * 2 + 1) * 4 + g) * 16 + c0) * 8];
            f32x4 hh[8];
            #pragma unroll
            for (int nt = 0; nt < 8; ++nt) {
                const bf8 w0 = *(const bf8*)&W1f[((0 * 4 + g) * D_ + nt * 16 + c0) * 8];
                const bf8 w1 = *(const bf8*)&W1f[((1 * 4 + g) * D_ + nt * 16 + c0) * 8];
                f32x4 acc = {0.f, 0.f, 0.f, 0.f};
                acc = __builtin_amdgcn_mfma_f32_16x16x32_bf16(a0, w0, acc, 0, 0, 0);
                acc = __builtin_amdgcn_mfma_f32_16x16x32_bf16(a1, w1, acc, 0, 0, 0);
                hh[nt] = acc;
            }
            // value (row m' = g*4+r, col k2 = nt*16+c0) -> A2[w][nt>>1][(nt&1)*2+(c0>>3)][m'][c0&7]
            // convert in pairs (1 cvt_pk per 2 values); halves store to their
            // strided rows ((short)pk -> b16, pk>>16 -> b16_d16_hi).
            #pragma unroll
            for (int nt = 0; nt < 8; ++nt) {
                const int shb = (((w * 4 + (nt >> 1)) * 4 + ((nt & 1) * 2 + (c0 >> 3))) * 16) * 8 + (c0 & 7);
                #pragma unroll
                for (int pr = 0; pr < 2; ++pr) {
                    const float h0 = ssp(hh[nt][2 * pr]     + b1r[nt]);
                    const float h1 = ssp(hh[nt][2 * pr + 1] + b1r[nt]);
                    const unsigned pk = cvt_pk_bf16(h0, h1);
                    A2[shb + (g * 4 + 2 * pr)     * 8] = (short)(pk & 0xFFFFu);
                    A2[shb + (g * 4 + 2 * pr + 1) * 8] = (short)(pk >> 16);
                }
            }
        }
        __syncthreads();   // (2) A2 ready

        // ===== Phase C: GEMM2 (filters = h1 @ W2), ssp, gather*filter, scatter =====
        {
            // gather loads issued FIRST in the drain-free window: idx was
            // prefetched last tile, so addresses are ready; GEMM2's 32 MFMAs
            // + 32 LDS b128 reads (~400-600 cyc) cover the gather latency.
            float rows[4][8];
            #pragma unroll
            for (int r = 0; r < 4; ++r) {
                const float* rowp = af_b + (size_t)idx[r] * D_ + c0;
                #pragma unroll
                for (int nt = 0; nt < 8; ++nt) rows[r][nt] = rowp[nt * 16];
            }

            const bf8 p0 = *(const bf8*)&A2[(((w * 4 + 0) * 4 + g) * 16 + c0) * 8];
            const bf8 p1 = *(const bf8*)&A2[(((w * 4 + 1) * 4 + g) * 16 + c0) * 8];
            const bf8 p2 = *(const bf8*)&A2[(((w * 4 + 2) * 4 + g) * 16 + c0) * 8];
            const bf8 p3 = *(const bf8*)&A2[(((w * 4 + 3) * 4 + g) * 16 + c0) * 8];
            f32x4 facc[8];
            #pragma unroll
            for (int nt = 0; nt < 8; ++nt) {
                const bf8 w0 = *(const bf8*)&W2f[((0 * 4 + g) * D_ + nt * 16 + c0) * 8];
                const bf8 w1 = *(const bf8*)&W2f[((1 * 4 + g) * D_ + nt * 16 + c0) * 8];
                const bf8 w2 = *(const bf8*)&W2f[((2 * 4 + g) * D_ + nt * 16 + c0) * 8];
                const bf8 w3 = *(const bf8*)&W2f[((3 * 4 + g) * D_ + nt * 16 + c0) * 8];
                f32x4 acc = {0.f, 0.f, 0.f, 0.f};
                acc = __builtin_amdgcn_mfma_f32_16x16x32_bf16(p0, w0, acc, 0, 0, 0);
                acc = __builtin_amdgcn_mfma_f32_16x16x32_bf16(p1, w1, acc, 0, 0, 0);
                acc = __builtin_amdgcn_mfma_f32_16x16x32_bf16(p2, w2, acc, 0, 0, 0);
                acc = __builtin_amdgcn_mfma_f32_16x16x32_bf16(p3, w3, acc, 0, 0, 0);
                facc[nt] = acc;
            }
            // epilogue: lane-quad g owns edges ebase + s*4 + r, lane handles cols c0+16*nt
            #pragma unroll
            for (int r = 0; r < 4; ++r) {
                const int sg = sgp[r];
                vf8 msg;
                #pragma unroll
                for (int nt = 0; nt < 8; ++nt) {
                    const float fv = ssp(facc[nt][r] + b2r[nt]);
                    msg[nt] = rows[r][nt] * fv;
                }
                if (sg != cur_seg) {
                    if (cur_seg >= 0) {
                        float* o = out_b + (size_t)cur_seg * D_ + c0;
                        #pragma unroll
                        for (int nt = 0; nt < 8; ++nt) atomicAdd(o + nt * 16, pend[nt]);
                    }
                    cur_seg = sg;
                    pend = msg;
                } else {
                    pend += msg;
                }
            }
        }

        // commit prefetched scalars for next tile
        dd = ddN;
        #pragma unroll
        for (int r = 0; r < 4; ++r) { idx[r] = idxN[r]; sgp[r] = sgN[r]; }
        // next Phase A writes A1 only after barrier (1); A2 race guarded by (1) too
    }
    if (cur_seg >= 0) {
        float* o = out_b + (size_t)cur_seg * D_ + c0;
        #pragma unroll
        for (int nt = 0; nt < 8; ++nt) atomicAdd(o + nt * 16, pend[nt]);
    }
}

extern "C" void kernel_launch(void* const* d_in, const int* in_sizes, int n_in,
                              void* d_out, int out_size, void* d_ws, size_t ws_size,
                              hipStream_t stream) {
    const float* af      = (const float*)d_in[0];
    const float* dist    = (const float*)d_in[1];
    const int*   idx_j   = (const int*)d_in[2];
    const int*   seg_i   = (const int*)d_in[3];
    const float* centers = (const float*)d_in[4];
    const float* gam     = (const float*)d_in[5];
    const float* W1      = (const float*)d_in[6];
    const float* b1      = (const float*)d_in[7];
    const float* W2      = (const float*)d_in[8];
    const float* b2      = (const float*)d_in[9];
    float* out = (float*)d_out;

    hipMemsetAsync(out, 0, (size_t)out_size * sizeof(float), stream);

    dim3 grid(NBLK, B_);
    cfconv_kernel<<<grid, TPB, 0, stream>>>(af, dist, idx_j, seg_i,
                                            centers, gam, W1, b1, W2, b2, out);
}